// Round 1
// baseline (39388.861 us; speedup 1.0000x reference)
//
#include <hip/hip_runtime.h>

// ---- problem constants ----
#define NT 365
#define NB 512          // ngrid == hidden
#define NH 512
#define NX4 16
#define NG 2048         // 4*H

typedef __attribute__((ext_vector_type(8))) short bf16x8;
typedef __attribute__((ext_vector_type(4))) float f32x4;
typedef unsigned short u16;
typedef unsigned int u32;

// ---- workspace layout (bytes) ----
static constexpr size_t WB_OFF  = 0;                                   // 4 x [2048][512] bf16
static constexpr size_t B0_OFF  = WB_OFF + 4ull * 2048 * 512 * 2;      // 2048 f32
static constexpr size_t B1_OFF  = B0_OFF + 2048 * 4;
static constexpr size_t X0_OFF  = B1_OFF + 2048 * 4;                   // [512][512] bf16
static constexpr size_t HT_OFF  = X0_OFF + 512 * 512 * 2;
static constexpr size_t HT0_OFF = HT_OFF + 512 * 512 * 2;
static constexpr size_t G0_OFF  = HT0_OFF + 512 * 512 * 2;             // 4 x [512][512] bf16 (activated L0 gates)
static constexpr size_t G1_OFF  = G0_OFF + 4ull * 512 * 512 * 2;       // 4 x [512][512] bf16 (raw L1 gates)
static constexpr size_t CT_OFF  = G1_OFF + 4ull * 512 * 512 * 2;       // [512][512] f32
static constexpr size_t VAR_OFF = CT_OFF + 512 * 512 * 4;              // [365][4][2] f32
static constexpr size_t BAR_OFF = (VAR_OFF + 365 * 8 * 4 + 255) & ~255ull; // 600 ints

__device__ __forceinline__ u16 f2bf(float f) {
  u32 u = __builtin_bit_cast(u32, f);
  return (u16)((u + 0x7fffu + ((u >> 16) & 1u)) >> 16);
}
__device__ __forceinline__ float sigf(float x) { return 1.0f / (1.0f + __expf(-x)); }
__device__ __forceinline__ float tanha(float x) { return 1.0f - 2.0f / (__expf(2.0f * x) + 1.0f); }

// 2-level grid barrier, monotonic counters. Requires grid == 256 (16 groups of 16).
__device__ __forceinline__ void gbar(int* bar, int gen) {
  __syncthreads();
  if (threadIdx.x == 0) {
    __threadfence();
    int grp = (int)blockIdx.x >> 4;
    int old = __hip_atomic_fetch_add(bar + grp * 32, 1, __ATOMIC_RELAXED, __HIP_MEMORY_SCOPE_AGENT);
    if ((old & 15) == 15) {
      int rold = __hip_atomic_fetch_add(bar + 512, 1, __ATOMIC_RELAXED, __HIP_MEMORY_SCOPE_AGENT);
      if ((rold & 15) == 15)
        __hip_atomic_store(bar + 544, gen + 1, __ATOMIC_RELEASE, __HIP_MEMORY_SCOPE_AGENT);
    }
    while (__hip_atomic_load(bar + 544, __ATOMIC_RELAXED, __HIP_MEMORY_SCOPE_AGENT) < gen + 1)
      __builtin_amdgcn_s_sleep(1);
    __threadfence();
  }
  __syncthreads();
}

// Stage A=[x|h] rows [rbase,rbase+32) into LDS (swizzled), then M=32,N=128,K=1024 MFMA.
// Wave w computes gate w's [32 x 32] tile (cols cbase..cbase+31). wbase = [Wih | Whh] bf16.
__device__ __forceinline__ void gemm_gates(
    const u16* __restrict__ xsrc, const u16* __restrict__ hsrc,
    const u16* __restrict__ wbase, char* lraw, int rbase, int cbase,
    int tid, f32x4 acc[2][2]) {
  const int w = tid >> 6, lane = tid & 63, l15 = lane & 15, kg = lane >> 4;
  const int xorv = (l15 & 7) << 4;
  #pragma unroll 4
  for (int i = 0; i < 16; ++i) {
    int ch = i * 256 + tid;
    int row = ch >> 7, cc = ch & 127;
    int k = cc << 3;
    const u16* sp = (k < 512) ? (xsrc + (size_t)(rbase + row) * 512 + k)
                              : (hsrc + (size_t)(rbase + row) * 512 + (k - 512));
    uint4 v = *(const uint4*)sp;
    *(uint4*)&lraw[(row << 11) | ((cc << 4) ^ ((row & 7) << 4))] = v;
  }
  __syncthreads();
  const int wrow = w * 512 + cbase + l15;
  #pragma unroll
  for (int half = 0; half < 2; ++half) {
    const u16* Wsrc = wbase + (size_t)half * 2048 * 512;
    const int kAb = half * 1024;
    #pragma unroll 4
    for (int ks = 0; ks < 16; ++ks) {
      int kk = ks * 32 + kg * 8;
      int ab = (kAb + kk * 2) ^ xorv;
      bf16x8 a0 = *(const bf16x8*)&lraw[(l15 << 11) | ab];
      bf16x8 a1 = *(const bf16x8*)&lraw[((16 + l15) << 11) | ab];
      bf16x8 q0 = *(const bf16x8*)(Wsrc + (size_t)wrow * 512 + kk);
      bf16x8 q1 = *(const bf16x8*)(Wsrc + (size_t)(wrow + 16) * 512 + kk);
      acc[0][0] = __builtin_amdgcn_mfma_f32_16x16x32_bf16(a0, q0, acc[0][0], 0, 0, 0);
      acc[1][0] = __builtin_amdgcn_mfma_f32_16x16x32_bf16(a1, q0, acc[1][0], 0, 0, 0);
      acc[0][1] = __builtin_amdgcn_mfma_f32_16x16x32_bf16(a0, q1, acc[0][1], 0, 0, 0);
      acc[1][1] = __builtin_amdgcn_mfma_f32_16x16x32_bf16(a1, q1, acc[1][1], 0, 0, 0);
    }
  }
  __syncthreads();
}

__global__ void init_k(float* __restrict__ out, const float* __restrict__ bout,
                       char* __restrict__ ws) {
  float* var = (float*)(ws + VAR_OFF);
  int* bar = (int*)(ws + BAR_OFF);
  int i = blockIdx.x * 256 + threadIdx.x;
  float bo = bout[0];
  for (int j = i; j < NT * NB; j += 256 * 256) out[j] = bo;
  if (i < NT * 8) var[i] = 0.0f;
  if (i < 600) bar[i] = 0;
  if (i == 0) out[NT * NB] = 0.0f;
}

__global__ __launch_bounds__(256, 1) void lstm_main(
    const float* __restrict__ xg, const float* __restrict__ Win, const float* __restrict__ bin,
    const float* __restrict__ Wih0, const float* __restrict__ bih0,
    const float* __restrict__ Whh0, const float* __restrict__ bhh0,
    const float* __restrict__ Wih1, const float* __restrict__ bih1,
    const float* __restrict__ Whh1, const float* __restrict__ bhh1,
    const float* __restrict__ Wout, float* __restrict__ out, char* __restrict__ ws) {
  __shared__ __align__(16) char lraw[65536];
  u16* wb = (u16*)(ws + WB_OFF);
  float* b0 = (float*)(ws + B0_OFF);
  float* b1 = (float*)(ws + B1_OFF);
  u16* x0b = (u16*)(ws + X0_OFF);
  u16* htb = (u16*)(ws + HT_OFF);
  u16* ht0b = (u16*)(ws + HT0_OFF);
  u16* g0b = (u16*)(ws + G0_OFF);
  u16* g1b = (u16*)(ws + G1_OFF);
  float* ctb = (float*)(ws + CT_OFF);
  float* var = (float*)(ws + VAR_OFF);
  int* bar = (int*)(ws + BAR_OFF);

  const int tid = threadIdx.x;
  const int gid = blockIdx.x;
  const int gtid = gid * 256 + tid;
  const int r = gid >> 4, c = gid & 15;      // c = gid%16 -> same-XCD wgs share weight slices
  const int rbase = r * 32, cbase = c * 32;
  const int w = tid >> 6, lane = tid & 63, l15 = lane & 15, kg = lane >> 4;

  // ================= prologue =================
  {
    const float* srcs[4] = {Wih0, Whh0, Wih1, Whh1};
    #pragma unroll
    for (int m = 0; m < 4; ++m) {
      const float4* s4 = (const float4*)srcs[m];
      ushort4* d4 = (ushort4*)(wb + (size_t)m * 2048 * 512);
      for (int i = gtid; i < 2048 * 512 / 4; i += 65536) {
        float4 v = s4[i];
        ushort4 o;
        o.x = f2bf(v.x); o.y = f2bf(v.y); o.z = f2bf(v.z); o.w = f2bf(v.w);
        d4[i] = o;
      }
    }
    if (gtid < 2048) { b0[gtid] = bih0[gtid] + bhh0[gtid]; b1[gtid] = bih1[gtid] + bhh1[gtid]; }
    for (int i = gtid; i < 512 * 512; i += 65536) ctb[i] = 0.0f;
    u32* hz = (u32*)htb;
    for (int i = gtid; i < 512 * 512 / 2; i += 65536) hz[i] = 0u;
    // x0 for t = 0 (4 consecutive h, one row b, per thread)
    {
      int e = gtid * 4;
      int b = e >> 9, h0 = e & 511;
      const float4* x4 = (const float4*)(xg + (size_t)b * NX4);
      float xv[16];
      *(float4*)&xv[0] = x4[0]; *(float4*)&xv[4] = x4[1];
      *(float4*)&xv[8] = x4[2]; *(float4*)&xv[12] = x4[3];
      ushort4 o; u16 tmp[4];
      #pragma unroll
      for (int j = 0; j < 4; ++j) {
        const float* wr = Win + (size_t)(h0 + j) * NX4;
        float a = bin[h0 + j];
        #pragma unroll
        for (int n = 0; n < 16; ++n) a += xv[n] * wr[n];
        tmp[j] = f2bf(fmaxf(a, 0.0f));
      }
      o.x = tmp[0]; o.y = tmp[1]; o.z = tmp[2]; o.w = tmp[3];
      *(ushort4*)(x0b + e) = o;
    }
  }
  int gen = 0;
  gbar(bar, gen); ++gen;

  // ================= time loop =================
  for (int t = 0; t < NT; ++t) {
    // ---- P1: layer-0 gates + cell update ----
    {
      f32x4 acc[2][2] = {};
      gemm_gates(x0b, htb, wb, lraw, rbase, cbase, tid, acc);
      float* gF = (float*)lraw;  // [4][32][32]
      #pragma unroll
      for (int n = 0; n < 2; ++n) {
        float bb = b0[w * 512 + cbase + n * 16 + l15];
        #pragma unroll
        for (int m = 0; m < 2; ++m)
          #pragma unroll
          for (int q = 0; q < 4; ++q) {
            float v = acc[m][n][q] + bb;
            float a = (w == 2) ? tanha(v) : sigf(v);
            gF[(w * 32 + m * 16 + kg * 4 + q) * 32 + n * 16 + l15] = a;
          }
      }
      __syncthreads();
      int row = tid >> 3, col0 = (tid & 7) * 4;
      int b = rbase + row, h0 = cbase + col0;
      float4 ct4 = *(float4*)(ctb + (size_t)b * 512 + h0);
      float ctv[4] = {ct4.x, ct4.y, ct4.z, ct4.w};
      float g4[4][4];
      #pragma unroll
      for (int g2 = 0; g2 < 4; ++g2)
        #pragma unroll
        for (int j = 0; j < 4; ++j) g4[g2][j] = gF[(g2 * 32 + row) * 32 + col0 + j];
      float ctn[4]; u16 hv[4];
      #pragma unroll
      for (int j = 0; j < 4; ++j) {
        ctn[j] = g4[1][j] * ctv[j] + g4[0][j] * g4[2][j];
        hv[j] = f2bf(g4[3][j] * tanha(ctn[j]));
      }
      *(float4*)(ctb + (size_t)b * 512 + h0) = make_float4(ctn[0], ctn[1], ctn[2], ctn[3]);
      ushort4 hp; hp.x = hv[0]; hp.y = hv[1]; hp.z = hv[2]; hp.w = hv[3];
      *(ushort4*)(ht0b + (size_t)b * 512 + h0) = hp;
      #pragma unroll
      for (int g2 = 0; g2 < 4; ++g2) {
        ushort4 gp;
        gp.x = f2bf(g4[g2][0]); gp.y = f2bf(g4[g2][1]);
        gp.z = f2bf(g4[g2][2]); gp.w = f2bf(g4[g2][3]);
        *(ushort4*)(g0b + (size_t)g2 * 262144 + (size_t)b * 512 + h0) = gp;
      }
    }
    gbar(bar, gen); ++gen;

    // ---- P2: layer-1 raw gates ----
    {
      f32x4 acc[2][2] = {};
      gemm_gates(x0b, ht0b, wb + 2ull * 2048 * 512, lraw, rbase, cbase, tid, acc);
      float* gF = (float*)lraw;
      #pragma unroll
      for (int n = 0; n < 2; ++n) {
        float bb = b1[w * 512 + cbase + n * 16 + l15];
        #pragma unroll
        for (int m = 0; m < 2; ++m)
          #pragma unroll
          for (int q = 0; q < 4; ++q)
            gF[(w * 32 + m * 16 + kg * 4 + q) * 32 + n * 16 + l15] = acc[m][n][q] + bb;
      }
      __syncthreads();
      int row = tid >> 3, col0 = (tid & 7) * 4;
      int b = rbase + row, h0 = cbase + col0;
      #pragma unroll
      for (int g2 = 0; g2 < 4; ++g2) {
        ushort4 gp;
        gp.x = f2bf(gF[(g2 * 32 + row) * 32 + col0 + 0]);
        gp.y = f2bf(gF[(g2 * 32 + row) * 32 + col0 + 1]);
        gp.z = f2bf(gF[(g2 * 32 + row) * 32 + col0 + 2]);
        gp.w = f2bf(gF[(g2 * 32 + row) * 32 + col0 + 3]);
        *(ushort4*)(g1b + (size_t)g2 * 262144 + (size_t)b * 512 + h0) = gp;
      }
    }
    gbar(bar, gen); ++gen;

    // ---- P3: [B,B] score matmuls + layer-1 update + outputs ----
    {
      f32x4 acc[2][2] = {};
      const u16* As = g0b + (size_t)w * 262144;
      const u16* Bs = g1b + (size_t)w * 262144;
      int ar = rbase + l15, br = cbase + l15;
      #pragma unroll 4
      for (int ks = 0; ks < 16; ++ks) {
        int kk = ks * 32 + kg * 8;
        bf16x8 a0 = *(const bf16x8*)(As + (size_t)ar * 512 + kk);
        bf16x8 a1 = *(const bf16x8*)(As + (size_t)(ar + 16) * 512 + kk);
        bf16x8 q0 = *(const bf16x8*)(Bs + (size_t)br * 512 + kk);
        bf16x8 q1 = *(const bf16x8*)(Bs + (size_t)(br + 16) * 512 + kk);
        acc[0][0] = __builtin_amdgcn_mfma_f32_16x16x32_bf16(a0, q0, acc[0][0], 0, 0, 0);
        acc[1][0] = __builtin_amdgcn_mfma_f32_16x16x32_bf16(a1, q0, acc[1][0], 0, 0, 0);
        acc[0][1] = __builtin_amdgcn_mfma_f32_16x16x32_bf16(a0, q1, acc[0][1], 0, 0, 0);
        acc[1][1] = __builtin_amdgcn_mfma_f32_16x16x32_bf16(a1, q1, acc[1][1], 0, 0, 0);
      }
      // variance partials for this gate tile
      float s1 = 0.0f, s2 = 0.0f;
      #pragma unroll
      for (int m = 0; m < 2; ++m)
        #pragma unroll
        for (int n = 0; n < 2; ++n)
          #pragma unroll
          for (int q = 0; q < 4; ++q) { float v = acc[m][n][q]; s1 += v; s2 += v * v; }
      #pragma unroll
      for (int off = 32; off > 0; off >>= 1) { s1 += __shfl_xor(s1, off); s2 += __shfl_xor(s2, off); }
      if (lane == 0) {
        atomicAdd(var + t * 8 + w * 2, s1);
        atomicAdd(var + t * 8 + w * 2 + 1, s2);
      }
      float* gF = (float*)lraw;
      #pragma unroll
      for (int n = 0; n < 2; ++n)
        #pragma unroll
        for (int m = 0; m < 2; ++m)
          #pragma unroll
          for (int q = 0; q < 4; ++q)
            gF[(w * 32 + m * 16 + kg * 4 + q) * 32 + n * 16 + l15] = acc[m][n][q];
      __syncthreads();
      int row = tid >> 3, col0 = (tid & 7) * 4;
      int b = rbase + row, h0 = cbase + col0;
      float4 ct4 = *(float4*)(ctb + (size_t)b * 512 + h0);
      float ctv[4] = {ct4.x, ct4.y, ct4.z, ct4.w};
      float htf[4]; u16 hv[4];
      #pragma unroll
      for (int j = 0; j < 4; ++j) {
        float i1 = sigf(gF[(0 * 32 + row) * 32 + col0 + j]);
        float f1 = sigf(gF[(1 * 32 + row) * 32 + col0 + j]);
        float c1 = tanha(gF[(2 * 32 + row) * 32 + col0 + j]);
        float o1 = sigf(gF[(3 * 32 + row) * 32 + col0 + j]);
        float cn = f1 * ctv[j] + i1 * c1;
        ctv[j] = cn;
        htf[j] = o1 * tanha(cn);
        hv[j] = f2bf(htf[j]);
      }
      *(float4*)(ctb + (size_t)b * 512 + h0) = make_float4(ctv[0], ctv[1], ctv[2], ctv[3]);
      ushort4 hp; hp.x = hv[0]; hp.y = hv[1]; hp.z = hv[2]; hp.w = hv[3];
      *(ushort4*)(htb + (size_t)b * 512 + h0) = hp;
      float op = htf[0] * Wout[h0] + htf[1] * Wout[h0 + 1] + htf[2] * Wout[h0 + 2] + htf[3] * Wout[h0 + 3];
      op += __shfl_down(op, 4, 8);
      op += __shfl_down(op, 2, 8);
      op += __shfl_down(op, 1, 8);
      if ((tid & 7) == 0) atomicAdd(out + (size_t)t * NB + b, op);
      // next step's input projection tile
      if (t + 1 < NT) {
        const float4* x4 = (const float4*)(xg + ((size_t)(t + 1) * NB + b) * NX4);
        float xv[16];
        *(float4*)&xv[0] = x4[0]; *(float4*)&xv[4] = x4[1];
        *(float4*)&xv[8] = x4[2]; *(float4*)&xv[12] = x4[3];
        u16 tmp[4];
        #pragma unroll
        for (int j = 0; j < 4; ++j) {
          const float* wr = Win + (size_t)(h0 + j) * NX4;
          float a = bin[h0 + j];
          #pragma unroll
          for (int n = 0; n < 16; ++n) a += xv[n] * wr[n];
          tmp[j] = f2bf(fmaxf(a, 0.0f));
        }
        ushort4 o; o.x = tmp[0]; o.y = tmp[1]; o.z = tmp[2]; o.w = tmp[3];
        *(ushort4*)(x0b + (size_t)b * 512 + h0) = o;
      }
    }
    gbar(bar, gen); ++gen;
  }

  // ================= epilogue: norm =================
  if (gid == 0) {
    float s = 0.0f;
    const float invN = 1.0f / 262144.0f;
    for (int i = tid; i < NT * 4; i += 256) {
      float sum = var[i * 2], sq = var[i * 2 + 1];
      float mean = sum * invN;
      s += (sq * invN - mean * mean) * 0.25f;
    }
    #pragma unroll
    for (int off = 32; off > 0; off >>= 1) s += __shfl_xor(s, off);
    float* gF = (float*)lraw;
    if (lane == 0) gF[w] = s;
    __syncthreads();
    if (tid == 0) out[NT * NB] = (gF[0] + gF[1] + gF[2] + gF[3]) / (float)NT;
  }
}

extern "C" void kernel_launch(void* const* d_in, const int* in_sizes, int n_in,
                              void* d_out, int out_size, void* d_ws, size_t ws_size,
                              hipStream_t stream) {
  const float* xg = (const float*)d_in[0];
  const float* Win = (const float*)d_in[1];
  const float* bin = (const float*)d_in[2];
  const float* Wih0 = (const float*)d_in[3];
  const float* bih0 = (const float*)d_in[4];
  const float* Whh0 = (const float*)d_in[5];
  const float* bhh0 = (const float*)d_in[6];
  const float* Wih1 = (const float*)d_in[7];
  const float* bih1 = (const float*)d_in[8];
  const float* Whh1 = (const float*)d_in[9];
  const float* bhh1 = (const float*)d_in[10];
  const float* Wout = (const float*)d_in[11];
  const float* bout = (const float*)d_in[12];
  float* out = (float*)d_out;
  char* ws = (char*)d_ws;

  hipLaunchKernelGGL(init_k, dim3(256), dim3(256), 0, stream, out, bout, ws);

  void* args[] = {(void*)&xg, (void*)&Win, (void*)&bin, (void*)&Wih0, (void*)&bih0,
                  (void*)&Whh0, (void*)&bhh0, (void*)&Wih1, (void*)&bih1,
                  (void*)&Whh1, (void*)&bhh1, (void*)&Wout, (void*)&out, (void*)&ws};
  hipLaunchCooperativeKernel((void*)lstm_main, dim3(256), dim3(256), args, 0, stream);
}

// Round 2
// 34674.384 us; speedup vs baseline: 1.1360x; 1.1360x over previous
//
#include <hip/hip_runtime.h>

// ---- problem constants ----
#define NT 365
#define NB 512          // ngrid == hidden
#define NX4 16

typedef __attribute__((ext_vector_type(8))) short bf16x8;
typedef __attribute__((ext_vector_type(4))) float f32x4;
typedef unsigned short u16;
typedef unsigned int u32;

// ---- workspace layout (bytes) ----
static constexpr size_t WB_OFF  = 0;                                   // 4 x [2048][512] bf16
static constexpr size_t B0_OFF  = WB_OFF + 4ull * 2048 * 512 * 2;      // 2048 f32
static constexpr size_t B1_OFF  = B0_OFF + 2048 * 4;
static constexpr size_t X0_OFF  = B1_OFF + 2048 * 4;                   // [512][512] bf16
static constexpr size_t HT_OFF  = X0_OFF + 512 * 512 * 2;
static constexpr size_t HT0_OFF = HT_OFF + 512 * 512 * 2;
static constexpr size_t G0_OFF  = HT0_OFF + 512 * 512 * 2;             // 4 x [512][512] bf16
static constexpr size_t G1_OFF  = G0_OFF + 4ull * 512 * 512 * 2;       // 4 x [512][512] bf16
static constexpr size_t VS_OFF  = G1_OFF + 4ull * 512 * 512 * 2;       // [8][512] f32 var partials
static constexpr size_t BAR_OFF = (VS_OFF + 8 * 512 * 4 + 255) & ~255ull; // 600 ints

__device__ __forceinline__ u16 f2bf(float f) {
  u32 u = __builtin_bit_cast(u32, f);
  return (u16)((u + 0x7fffu + ((u >> 16) & 1u)) >> 16);
}
__device__ __forceinline__ float bf2f(u16 h) {
  u32 u = ((u32)h) << 16;
  return __builtin_bit_cast(float, u);
}
__device__ __forceinline__ float sigf(float x) { return 1.0f / (1.0f + __expf(-x)); }
__device__ __forceinline__ float tanha(float x) { return 1.0f - 2.0f / (__expf(2.0f * x) + 1.0f); }

// 2-level grid barrier, monotonic counters. Requires grid == 256 (16 groups of 16).
__device__ __forceinline__ void gbar(int* bar, int gen) {
  __syncthreads();
  if (threadIdx.x == 0) {
    __threadfence();
    int grp = (int)blockIdx.x >> 4;
    int old = __hip_atomic_fetch_add(bar + grp * 32, 1, __ATOMIC_RELAXED, __HIP_MEMORY_SCOPE_AGENT);
    if ((old & 15) == 15) {
      int rold = __hip_atomic_fetch_add(bar + 512, 1, __ATOMIC_RELAXED, __HIP_MEMORY_SCOPE_AGENT);
      if ((rold & 15) == 15)
        __hip_atomic_store(bar + 544, gen + 1, __ATOMIC_RELEASE, __HIP_MEMORY_SCOPE_AGENT);
    }
    while (__hip_atomic_load(bar + 544, __ATOMIC_RELAXED, __HIP_MEMORY_SCOPE_AGENT) < gen + 1)
      __builtin_amdgcn_s_sleep(1);
    __threadfence();
  }
  __syncthreads();
}

__global__ void init_k(float* __restrict__ out, const float* __restrict__ bout,
                       char* __restrict__ ws) {
  float* vsb = (float*)(ws + VS_OFF);
  int* bar = (int*)(ws + BAR_OFF);
  int i = blockIdx.x * 256 + threadIdx.x;
  float bo = bout[0];
  for (int j = i; j < NT * NB; j += 256 * 256) out[j] = bo;
  if (i < 8 * 512) vsb[i] = 0.0f;
  if (i < 600) bar[i] = 0;
  if (i == 0) out[NT * NB] = 0.0f;
}

__global__ __launch_bounds__(1024, 4) void lstm_main(
    const float* __restrict__ xg, const float* __restrict__ Win, const float* __restrict__ bin,
    const float* __restrict__ Wih0, const float* __restrict__ bih0,
    const float* __restrict__ Whh0, const float* __restrict__ bhh0,
    const float* __restrict__ Wih1, const float* __restrict__ bih1,
    const float* __restrict__ Whh1, const float* __restrict__ bhh1,
    const float* __restrict__ Wout, float* __restrict__ out, char* __restrict__ ws) {
  __shared__ __align__(16) char lraw[65536];
  u16* gFu = (u16*)lraw;               // [4][32][40] bf16 (aliased over staging)
  float* sv = (float*)(lraw + 32768);  // [16][2] f32 var partials (aliased)
  u16* wb = (u16*)(ws + WB_OFF);
  float* b0 = (float*)(ws + B0_OFF);
  float* b1 = (float*)(ws + B1_OFF);
  u16* x0b = (u16*)(ws + X0_OFF);
  u16* htb = (u16*)(ws + HT_OFF);
  u16* ht0b = (u16*)(ws + HT0_OFF);
  u16* g0b = (u16*)(ws + G0_OFF);
  u16* g1b = (u16*)(ws + G1_OFF);
  float* vsb = (float*)(ws + VS_OFF);
  int* bar = (int*)(ws + BAR_OFF);

  const int tid = threadIdx.x;
  const int gid = blockIdx.x;
  const int gtid = gid * 1024 + tid;
  const int r = gid >> 4, c = gid & 15;   // same-c wgs land on one XCD (gid%8 dispatch)
  const int rbase = r * 32, cbase = c * 32;
  const int w = tid >> 6, lane = tid & 63, l15 = lane & 15, kg = lane >> 4;
  const int g = w >> 2, m = (w >> 1) & 1, n = w & 1;  // wave's fragment: gate g, m/n halves
  const int urow = tid >> 5, ucol = tid & 31;          // update-phase element
  const int ub = rbase + urow, uh = cbase + ucol;

  // loop-invariant per-thread preloads
  float winr[16];
  #pragma unroll
  for (int j = 0; j < 16; ++j) winr[j] = Win[(size_t)uh * NX4 + j];
  const float binr = bin[uh];
  const float woutr = Wout[uh];

  // ================= prologue =================
  {
    const float* srcs[4] = {Wih0, Whh0, Wih1, Whh1};
    #pragma unroll
    for (int mm = 0; mm < 4; ++mm) {
      const float4* s4 = (const float4*)srcs[mm];
      ushort4* d4 = (ushort4*)(wb + (size_t)mm * 2048 * 512);
      float4 v = s4[gtid];
      ushort4 o;
      o.x = f2bf(v.x); o.y = f2bf(v.y); o.z = f2bf(v.z); o.w = f2bf(v.w);
      d4[gtid] = o;
    }
    if (gtid < 2048) { b0[gtid] = bih0[gtid] + bhh0[gtid]; b1[gtid] = bih1[gtid] + bhh1[gtid]; }
    if (gtid < 512 * 512 / 2) ((u32*)htb)[gtid] = 0u;
    // x0 for t = 0: one element (ub, uh) per thread
    {
      const float* xr = xg + (size_t)ub * NX4;
      float a = binr;
      #pragma unroll
      for (int j = 0; j < 16; ++j) a += winr[j] * xr[j];
      x0b[(size_t)ub * 512 + uh] = f2bf(fmaxf(a, 0.0f));
    }
  }
  int gen = 0;
  gbar(bar, gen); ++gen;

  const float bias0l = b0[g * 512 + cbase + n * 16 + l15];
  const float bias1l = b1[g * 512 + cbase + n * 16 + l15];
  const int arow = m * 16 + l15;
  const int abase = arow << 11;
  const int axor = (arow & 7) << 4;
  const u16* Wl0 = wb + (size_t)(g * 512 + cbase + n * 16 + l15) * 512;  // Wih0 row
  float ctreg = 0.0f;  // this thread's cell-state element — never touches memory

  // ================= time loop =================
  for (int t = 0; t < NT; ++t) {
    // ---- P1: layer-0 gates + cell update ----
    #pragma unroll
    for (int p = 0; p < 4; ++p) {   // stage [x0 | ht] rows rbase..+32 (64KB, swizzled)
      int ch = p * 1024 + tid;
      int row = ch >> 7, cc = ch & 127;
      const u16* sp = (cc < 64) ? x0b + (size_t)(rbase + row) * 512 + cc * 8
                                : htb + (size_t)(rbase + row) * 512 + (cc - 64) * 8;
      uint4 v = *(const uint4*)sp;
      *(uint4*)&lraw[(row << 11) | ((cc << 4) ^ ((row & 7) << 4))] = v;
    }
    __syncthreads();
    {
      f32x4 acc = {0.f, 0.f, 0.f, 0.f};
      const u16* W0 = Wl0;                       // x-half weights
      const u16* W1 = Wl0 + 2048ull * 512;       // h-half weights (Whh0)
      #pragma unroll 4
      for (int ks = 0; ks < 16; ++ks) {
        int kk = ks * 32 + kg * 8;
        bf16x8 a = *(const bf16x8*)&lraw[abase | (((kk >> 3) << 4) ^ axor)];
        bf16x8 q = *(const bf16x8*)(W0 + kk);
        acc = __builtin_amdgcn_mfma_f32_16x16x32_bf16(a, q, acc, 0, 0, 0);
      }
      #pragma unroll 4
      for (int ks = 0; ks < 16; ++ks) {
        int kk = ks * 32 + kg * 8;
        bf16x8 a = *(const bf16x8*)&lraw[abase | (((64 + (kk >> 3)) << 4) ^ axor)];
        bf16x8 q = *(const bf16x8*)(W1 + kk);
        acc = __builtin_amdgcn_mfma_f32_16x16x32_bf16(a, q, acc, 0, 0, 0);
      }
      __syncthreads();  // staging dead; reuse LDS as gFu
      #pragma unroll
      for (int q = 0; q < 4; ++q) {
        float v = acc[q] + bias0l;
        float a = (g == 2) ? tanha(v) : sigf(v);
        gFu[g * 1280 + (m * 16 + kg * 4 + q) * 40 + n * 16 + l15] = f2bf(a);
      }
    }
    __syncthreads();
    {
      u16 gi = gFu[0 * 1280 + urow * 40 + ucol];
      u16 gf = gFu[1 * 1280 + urow * 40 + ucol];
      u16 gc = gFu[2 * 1280 + urow * 40 + ucol];
      u16 go = gFu[3 * 1280 + urow * 40 + ucol];
      float i0 = bf2f(gi), f0 = bf2f(gf), c0 = bf2f(gc), o0 = bf2f(go);
      ctreg = f0 * ctreg + i0 * c0;
      float h0v = o0 * tanha(ctreg);
      size_t eo = (size_t)ub * 512 + uh;
      ht0b[eo] = f2bf(h0v);
      g0b[0 * 262144 + eo] = gi;
      g0b[1 * 262144 + eo] = gf;
      g0b[2 * 262144 + eo] = gc;
      g0b[3 * 262144 + eo] = go;
    }
    gbar(bar, gen); ++gen;

    // ---- P2: layer-1 raw gates (direct global write, no redistribution) ----
    #pragma unroll
    for (int p = 0; p < 4; ++p) {   // stage [x0 | ht0]
      int ch = p * 1024 + tid;
      int row = ch >> 7, cc = ch & 127;
      const u16* sp = (cc < 64) ? x0b + (size_t)(rbase + row) * 512 + cc * 8
                                : ht0b + (size_t)(rbase + row) * 512 + (cc - 64) * 8;
      uint4 v = *(const uint4*)sp;
      *(uint4*)&lraw[(row << 11) | ((cc << 4) ^ ((row & 7) << 4))] = v;
    }
    __syncthreads();
    {
      f32x4 acc = {0.f, 0.f, 0.f, 0.f};
      const u16* W0 = Wl0 + 2ull * 2048 * 512;   // Wih1
      const u16* W1 = Wl0 + 3ull * 2048 * 512;   // Whh1
      #pragma unroll 4
      for (int ks = 0; ks < 16; ++ks) {
        int kk = ks * 32 + kg * 8;
        bf16x8 a = *(const bf16x8*)&lraw[abase | (((kk >> 3) << 4) ^ axor)];
        bf16x8 q = *(const bf16x8*)(W0 + kk);
        acc = __builtin_amdgcn_mfma_f32_16x16x32_bf16(a, q, acc, 0, 0, 0);
      }
      #pragma unroll 4
      for (int ks = 0; ks < 16; ++ks) {
        int kk = ks * 32 + kg * 8;
        bf16x8 a = *(const bf16x8*)&lraw[abase | (((64 + (kk >> 3)) << 4) ^ axor)];
        bf16x8 q = *(const bf16x8*)(W1 + kk);
        acc = __builtin_amdgcn_mfma_f32_16x16x32_bf16(a, q, acc, 0, 0, 0);
      }
      #pragma unroll
      for (int q = 0; q < 4; ++q) {
        int b_ = rbase + m * 16 + kg * 4 + q;
        g1b[(size_t)g * 262144 + (size_t)b_ * 512 + cbase + n * 16 + l15] = f2bf(acc[q] + bias1l);
      }
    }
    gbar(bar, gen); ++gen;

    // ---- P3: [B,B] score matmuls + layer-1 update + outputs ----
    {
      f32x4 acc = {0.f, 0.f, 0.f, 0.f};
      const u16* As = g0b + (size_t)g * 262144 + (size_t)(rbase + m * 16 + l15) * 512;
      const u16* Bs = g1b + (size_t)g * 262144 + (size_t)(cbase + n * 16 + l15) * 512;
      #pragma unroll 4
      for (int ks = 0; ks < 16; ++ks) {
        int kk = ks * 32 + kg * 8;
        bf16x8 a = *(const bf16x8*)(As + kk);
        bf16x8 q = *(const bf16x8*)(Bs + kk);
        acc = __builtin_amdgcn_mfma_f32_16x16x32_bf16(a, q, acc, 0, 0, 0);
      }
      float s1 = acc[0] + acc[1] + acc[2] + acc[3];
      float s2 = acc[0] * acc[0] + acc[1] * acc[1] + acc[2] * acc[2] + acc[3] * acc[3];
      #pragma unroll
      for (int off = 32; off > 0; off >>= 1) { s1 += __shfl_xor(s1, off); s2 += __shfl_xor(s2, off); }
      if (lane == 0) { sv[w * 2] = s1; sv[w * 2 + 1] = s2; }
      #pragma unroll
      for (int q = 0; q < 4; ++q)
        gFu[g * 1280 + (m * 16 + kg * 4 + q) * 40 + n * 16 + l15] = f2bf(acc[q]);
    }
    __syncthreads();
    {
      float i1 = sigf(bf2f(gFu[0 * 1280 + urow * 40 + ucol]));
      float f1 = sigf(bf2f(gFu[1 * 1280 + urow * 40 + ucol]));
      float c1 = tanha(bf2f(gFu[2 * 1280 + urow * 40 + ucol]));
      float o1 = sigf(bf2f(gFu[3 * 1280 + urow * 40 + ucol]));
      ctreg = f1 * ctreg + i1 * c1;
      float hv = o1 * tanha(ctreg);
      htb[(size_t)ub * 512 + uh] = f2bf(hv);
      float op = hv * woutr;
      op += __shfl_down(op, 16, 32);
      op += __shfl_down(op, 8, 32);
      op += __shfl_down(op, 4, 32);
      op += __shfl_down(op, 2, 32);
      op += __shfl_down(op, 1, 32);
      if ((tid & 31) == 0) atomicAdd(out + (size_t)t * NB + ub, op);
      if (tid < 8) {
        int gg = tid >> 1, part = tid & 1;
        float val = sv[(gg * 4 + 0) * 2 + part] + sv[(gg * 4 + 1) * 2 + part] +
                    sv[(gg * 4 + 2) * 2 + part] + sv[(gg * 4 + 3) * 2 + part];
        atomicAdd(vsb + (size_t)(gg * 2 + part) * 512 + t, val);
      }
      if (t + 1 < NT) {
        const float* xr = xg + ((size_t)(t + 1) * NB + ub) * NX4;
        float a = binr;
        #pragma unroll
        for (int j = 0; j < 16; ++j) a += winr[j] * xr[j];
        x0b[(size_t)ub * 512 + uh] = f2bf(fmaxf(a, 0.0f));
      }
    }
    gbar(bar, gen); ++gen;
  }

  // ================= epilogue: norm =================
  if (gid == 0) {
    float s = 0.0f;
    const float invN = 1.0f / 262144.0f;
    for (int i = tid; i < 4 * NT; i += 1024) {
      int gg = i / NT, tt = i - gg * NT;
      float sum = vsb[(size_t)(gg * 2) * 512 + tt];
      float sq = vsb[(size_t)(gg * 2 + 1) * 512 + tt];
      float mean = sum * invN;
      s += (sq * invN - mean * mean) * 0.25f;
    }
    #pragma unroll
    for (int off = 32; off > 0; off >>= 1) s += __shfl_xor(s, off);
    float* red = (float*)lraw;
    if (lane == 0) red[w] = s;
    __syncthreads();
    if (tid == 0) {
      float tot = 0.0f;
      #pragma unroll
      for (int j = 0; j < 16; ++j) tot += red[j];
      out[NT * NB] = tot / (float)NT;
    }
  }
}

extern "C" void kernel_launch(void* const* d_in, const int* in_sizes, int n_in,
                              void* d_out, int out_size, void* d_ws, size_t ws_size,
                              hipStream_t stream) {
  const float* xg = (const float*)d_in[0];
  const float* Win = (const float*)d_in[1];
  const float* bin = (const float*)d_in[2];
  const float* Wih0 = (const float*)d_in[3];
  const float* bih0 = (const float*)d_in[4];
  const float* Whh0 = (const float*)d_in[5];
  const float* bhh0 = (const float*)d_in[6];
  const float* Wih1 = (const float*)d_in[7];
  const float* bih1 = (const float*)d_in[8];
  const float* Whh1 = (const float*)d_in[9];
  const float* bhh1 = (const float*)d_in[10];
  const float* Wout = (const float*)d_in[11];
  const float* bout = (const float*)d_in[12];
  float* out = (float*)d_out;
  char* ws = (char*)d_ws;

  hipLaunchKernelGGL(init_k, dim3(256), dim3(256), 0, stream, out, bout, ws);

  void* args[] = {(void*)&xg, (void*)&Win, (void*)&bin, (void*)&Wih0, (void*)&bih0,
                  (void*)&Whh0, (void*)&bhh0, (void*)&Wih1, (void*)&bih1,
                  (void*)&Whh1, (void*)&bhh1, (void*)&Wout, (void*)&out, (void*)&ws};
  hipLaunchCooperativeKernel((void*)lstm_main, dim3(256), dim3(1024), args, 0, stream);
}